// Round 11
// baseline (123.078 us; speedup 1.0000x reference)
//
#include <hip/hip_runtime.h>
#include <hip/hip_bf16.h>

#define NN 8192
#define DD 128

typedef short short8 __attribute__((ext_vector_type(8)));
typedef __bf16 bf16x8 __attribute__((ext_vector_type(8)));
typedef float f32x4 __attribute__((ext_vector_type(4)));
typedef float f32x2 __attribute__((ext_vector_type(2)));

// unit-norm simplification (x2=y2=1):
//   tK = 2c(1-s)/(1-c)^2 ; dk = tK + 1 EXACTLY (dk-tK=1 identity)
//   rr = 2*sqrt(fma(tK,tK,tK)) + fma(tK,2,1)   [R29 folded identity]
//   lg = log2(rr) ; e = exp2(KE*lg)
// MODEL (R29 validated): fused = 49us; VALU issue ~20us (42%), MFMA 7%,
// ~50% dependency stall at ~3 waves/SIMD. All structural levers dead:
// cooperative launch (R20, graph capture), dispatch merging / atomic
// placement (R21/R22/R24, non-fused ~62us fixed harness work), register
// prefetch (R26: >64 VGPR -> occupancy cliff), 2048 thin blocks (R27:
// per-block fixed cost), manual vmcnt staging (R28: scheduling wall).
// NEVER launch_bounds(256,4): 64-VGPR cap -> ~1GB scratch spill (R8/R9).
// THIS ROUND (R30, final micro-cut): col credit via 2 wave-private LDS
// ds_add_f32 per lane (4-way same-address ~1.58x one DS op, m136) replacing
// the serial 4x ds_swizzle chain + exec-masked RMW (~16 instr/ct). Isolated
// test of R28's component b. If neutral -> design plateau, revert & stop.
#define MKc (-0.110803324099723f)   // -2c/(1-c)^2
#define PKc (0.110803324099723f)    // +2c/(1-c)^2
#define KEc (-8.944271909999159f)   // -1/(sqrt_c*T)
#define KLc (-6.199696797323639f)   // KE*ln2

// ---------------- prep: normalize 16 rows/block -> bf16; zero accumulators ----------------
__global__ __launch_bounds__(256) void prep_kernel(const float* __restrict__ x,
                                                   __hip_bfloat16* __restrict__ fb,
                                                   float* __restrict__ totg,
                                                   float* __restrict__ tposg,
                                                   float* __restrict__ scal,
                                                   int* __restrict__ dcnt) {
  int r = threadIdx.x >> 4, sub = threadIdx.x & 15;
  int row = blockIdx.x * 16 + r;
  const float4 a = *(const float4*)(x + (size_t)row * DD + sub * 8);
  const float4 b = *(const float4*)(x + (size_t)row * DD + sub * 8 + 4);
  float ss = a.x * a.x + a.y * a.y + a.z * a.z + a.w * a.w +
             b.x * b.x + b.y * b.y + b.z * b.z + b.w * b.w;
  for (int off = 1; off < 16; off <<= 1) ss += __shfl_xor(ss, off, 16);
  float inv = 1.0f / fmaxf(sqrtf(ss), 1e-12f);
  float va[8] = {a.x, a.y, a.z, a.w, b.x, b.y, b.z, b.w};
  short8 h;
  for (int j = 0; j < 8; j++) {
    __hip_bfloat16 t = __float2bfloat16(va[j] * inv);
    h[j] = __builtin_bit_cast(short, t);
  }
  *(short8*)((short*)fb + (size_t)row * DD + sub * 8) = h;
  if (threadIdx.x < 16) {
    totg[blockIdx.x * 16 + threadIdx.x] = 0.f;
    tposg[blockIdx.x * 16 + threadIdx.x] = 0.f;
  } else if (blockIdx.x == 0 && threadIdx.x < 20) {
    if (threadIdx.x == 16) scal[0] = 0.f;
    if (threadIdx.x == 17) scal[1] = 0.f;
    if (threadIdx.x == 18) dcnt[0] = 0;
    if (threadIdx.x == 19) dcnt[1] = 0;
  }
}

// ---------------- fused symmetric, pair-balanced: 1024 blocks x 16-17 cts ----------------
__global__ __launch_bounds__(256, 2) void fused_kernel(
    const __hip_bfloat16* __restrict__ fbg,
    const int* __restrict__ plab, const int* __restrict__ slab,
    float* __restrict__ totg, float* __restrict__ tposg) {
  __shared__ float colT_l[4 * 272];    // per-wave col e-sums   (4352 B)
  __shared__ float colG_l[4 * 272];    // per-wave col lg-sums  (4352 B)

  const int tid = threadIdx.x;
  const int w = tid >> 6;
  const int lane = tid & 63;
  const int lrow = lane & 15;
  const int quad = lane >> 4;

  // block -> (unit u, slot k) -> ct window [s, s+c) over the unit's 520 cts
  const int u = blockIdx.x >> 5;
  const int k = blockIdx.x & 31;
  const int s = (k < 8) ? 17 * k : 16 * k + 8;
  const int c = (k < 8) ? 17 : 16;
  const int B = 8 * (u + 1);  // strip u's ct count; cts >= B belong to strip 63-u

  // segments: [0]=strip u part, [1]=strip 63-u part (at most one block straddles)
  const int aEnd = min(s + c, B);
  const int aCnt = max(0, aEnd - s);
  const int bStart = max(s, B);
  const int bCnt = max(0, s + c - bStart);
  int segR0[2], segCol[2], segCnt[2], segLds[2];
  segR0[0] = 128 * u;        segCol[0] = s * 16;              segCnt[0] = aCnt; segLds[0] = 0;
  segR0[1] = 128 * (63 - u); segCol[1] = (bStart - B) * 16;   segCnt[1] = bCnt; segLds[1] = aCnt;

  // zero this wave's col-credit region (wave-private, no sync needed)
  for (int i = lane; i < 272; i += 64) {
    colT_l[w * 272 + i] = 0.f;
    colG_l[w * 272 + i] = 0.f;
  }

  const f32x2 MK2 = {MKc, MKc}, PK2 = {PKc, PKc};
  const f32x2 KE2 = {KEc, KEc}, ZERO2 = {0.f, 0.f};
  const f32x2 ONE2 = {1.f, 1.f}, TWO2 = {2.f, 2.f};

  for (int seg = 0; seg < 2; seg++) {
    const int cnt = segCnt[seg];
    if (cnt == 0) continue;
    const int R0 = segR0[seg];
    const int colBase = segCol[seg];
    const int ldsBase = segLds[seg];

    // A fragments + row labels (wave w owns rows R0 + w*32 .. +31, 2 strips of 16)
    bf16x8 af[2][4];
    int plr[2][4], slr[2][4];
    for (int strip = 0; strip < 2; strip++) {
      const short* fa = (const short*)fbg + (size_t)(R0 + w * 32 + strip * 16 + lrow) * DD;
      for (int kk = 0; kk < 4; kk++)
        af[strip][kk] = __builtin_bit_cast(bf16x8, *(const short8*)(fa + kk * 32 + quad * 8));
      for (int r = 0; r < 4; r++) {
        int rowg = R0 + w * 32 + strip * 16 + quad * 4 + r;
        plr[strip][r] = plab[rowg];
        slr[strip][r] = slab[rowg];
      }
    }

    f32x2 t2[2][2], g2[2][2];
    for (int s_ = 0; s_ < 2; s_++)
      for (int p = 0; p < 2; p++) { t2[s_][p] = ZERO2; g2[s_][p] = ZERO2; }

    const short* bp = (const short*)fbg + (size_t)(colBase + lrow) * DD + quad * 8;
    int colg = colBase + lrow;

    for (int ct = 0; ct < cnt; ct++) {
      bf16x8 bf[4];
      for (int kk = 0; kk < 4; kk++)
        bf[kk] = __builtin_bit_cast(bf16x8, *(const short8*)(bp + kk * 32));
      bp += 16 * DD;

      f32x4 acc[2];
      for (int strip = 0; strip < 2; strip++) {
        f32x4 a0 = {0.f, 0.f, 0.f, 0.f};
        for (int kk = 0; kk < 4; kk++)
          a0 = __builtin_amdgcn_mfma_f32_16x16x32_bf16(af[strip][kk], bf[kk], a0, 0, 0, 0);
        acc[strip] = a0;
      }

      const int pc = plab[colg];
      const int sc = slab[colg];
      const bool mct = (colg - lrow + 240 >= R0);  // conservative: ct's cols can reach rows
      f32x2 colE = ZERO2, colL = ZERO2;

      for (int strip = 0; strip < 2; strip++) {
        for (int p = 0; p < 2; p++) {
          f32x2 s2 = {acc[strip][2 * p], acc[strip][2 * p + 1]};
          // R29 chain: tK = max(fma(s,MK,PK),0); rr = 2*sqrt(tK*(tK+1)) + 2tK+1
          f32x2 tK = __builtin_elementwise_fma(s2, MK2, PK2);
          tK = __builtin_elementwise_max(tK, ZERO2);
          f32x2 m = __builtin_elementwise_fma(tK, tK, tK);
          f32x2 sq = {__builtin_amdgcn_sqrtf(m.x), __builtin_amdgcn_sqrtf(m.y)};
          f32x2 t2p1 = __builtin_elementwise_fma(tK, TWO2, ONE2);
          f32x2 rr = __builtin_elementwise_fma(sq, TWO2, t2p1);
          f32x2 lg = {__log2f(rr.x), __log2f(rr.y)};
          f32x2 el = KE2 * lg;
          f32x2 e = {exp2f(el.x), exp2f(el.y)};
          const int r0 = 2 * p, r1 = 2 * p + 1;
          bool same0 = (pc == plr[strip][r0]) || (sc == slr[strip][r0]);
          bool same1 = (pc == plr[strip][r1]) || (sc == slr[strip][r1]);
          f32x2 em, lm;
          if (mct) {
            int rg0 = R0 + w * 32 + strip * 16 + quad * 4 + r0;
            bool ok0 = (colg < rg0);
            bool ok1 = (colg < rg0 + 1);
            em.x = ok0 ? e.x : 0.f;
            em.y = ok1 ? e.y : 0.f;
            lm.x = (same0 && ok0) ? lg.x : 0.f;
            lm.y = (same1 && ok1) ? lg.y : 0.f;
          } else {
            em = e;
            lm.x = same0 ? lg.x : 0.f;
            lm.y = same1 ? lg.y : 0.f;
          }
          t2[strip][p] += em;
          g2[strip][p] += lm;
          colE += em;
          colL += lm;
        }
      }

      // R30 col credit: wave-private LDS atomics by all lanes (4 quads hit
      // the same slot -> 4-way same-address ds_add, ~1.6x one DS op). Replaces
      // the serial 4x ds_swizzle chain + exec-masked RMW (~16 instr/ct).
      atomicAdd(&colT_l[w * 272 + (ldsBase + ct) * 16 + lrow], colE.x + colE.y);
      atomicAdd(&colG_l[w * 272 + (ldsBase + ct) * 16 + lrow], colL.x + colL.y);
      colg += 16;
    }

    // row-side flush for this segment: 16-lane reduce, per-row atomics
    for (int strip = 0; strip < 2; strip++) {
      for (int r = 0; r < 4; r++) {
        float t = t2[strip][r >> 1][r & 1];
        float g = g2[strip][r >> 1][r & 1];
        for (int off = 1; off < 16; off <<= 1) {
          t += __shfl_xor(t, off, 16);
          g += __shfl_xor(g, off, 16);
        }
        if (lrow == 0) {
          int rowg = R0 + w * 32 + strip * 16 + quad * 4 + r;
          atomicAdd(&totg[rowg], t);
          atomicAdd(&tposg[rowg], g);
        }
      }
    }
  }

  // col-side flush: combine the 4 wave regions, one atomic per col per block
  __syncthreads();
  const int total = (aCnt + bCnt) * 16;
  for (int i = tid; i < total; i += 256) {
    const int ct = i >> 4;
    const int cin = i & 15;
    int col;
    if (ct < aCnt) col = segCol[0] + (ct - segLds[0]) * 16 + cin;
    else col = segCol[1] + (ct - segLds[1]) * 16 + cin;
    float sE = colT_l[i] + colT_l[272 + i] + colT_l[544 + i] + colT_l[816 + i];
    float sL = colG_l[i] + colG_l[272 + i] + colG_l[544 + i] + colG_l[816 + i];
    atomicAdd(&totg[col], sE);
    atomicAdd(&tposg[col], sL);
  }
}

// ---------------- finalize: 32 blocks x 256 threads, 1 row/thread ----------------
__global__ __launch_bounds__(256) void finalize_k(const float* __restrict__ totg,
                                                  const float* __restrict__ tposg,
                                                  const int* __restrict__ plab,
                                                  const int* __restrict__ slab,
                                                  float* __restrict__ scal,
                                                  int* __restrict__ dcnt,
                                                  float* __restrict__ out) {
  __shared__ int hist[512];
  __shared__ int cntP[32], cntS[16];
  __shared__ float redP[4], redV[4];
  const int tid = threadIdx.x;
  hist[tid] = 0;
  hist[tid + 256] = 0;
  __syncthreads();
  for (int i = tid; i < NN; i += 256)
    atomicAdd(&hist[plab[i] * 16 + slab[i]], 1);
  __syncthreads();
  if (tid < 32) {
    int s = 0;
    for (int j = 0; j < 16; j++) s += hist[tid * 16 + j];
    cntP[tid] = s;
  } else if (tid < 48) {
    int s = 0;
    for (int j = 0; j < 32; j++) s += hist[j * 16 + (tid - 32)];
    cntS[tid - 32] = s;
  }
  __syncthreads();
  const int row = blockIdx.x * 256 + tid;
  const int pl = plab[row], sl = slab[row];
  const int np = cntP[pl] + cntS[sl] - hist[pl * 16 + sl] - 1;
  float accP = 0.f, accV = 0.f;
  if (np > 0) {
    accP = (KLc * tposg[row]) / (float)np - __logf(totg[row] + 1e-8f);
    accV = 1.f;
  }
  for (int off = 32; off; off >>= 1) {
    accP += __shfl_xor(accP, off, 64);
    accV += __shfl_xor(accV, off, 64);
  }
  if ((tid & 63) == 0) { redP[tid >> 6] = accP; redV[tid >> 6] = accV; }
  __syncthreads();
  if (tid == 0) {
    atomicAdd(&scal[0], redP[0] + redP[1] + redP[2] + redP[3]);
    atomicAdd(&scal[1], redV[0] + redV[1] + redV[2] + redV[3]);
    __threadfence();
    if (atomicAdd(dcnt, 1) == 31) {  // last arriver writes the loss
      const float sp = __hip_atomic_load(&scal[0], __ATOMIC_ACQUIRE,
                                         __HIP_MEMORY_SCOPE_AGENT);
      const float sv = __hip_atomic_load(&scal[1], __ATOMIC_ACQUIRE,
                                         __HIP_MEMORY_SCOPE_AGENT);
      float loss = -(sp / fmaxf(sv, 1.0f)) * 0.5f;  // * TEMPERATURE
      if (sv <= 0.0f || !__builtin_isfinite(loss)) loss = 0.0f;
      out[0] = loss;
    }
  }
}

extern "C" void kernel_launch(void* const* d_in, const int* in_sizes, int n_in,
                              void* d_out, int out_size, void* d_ws, size_t ws_size,
                              hipStream_t stream) {
  const float* x = (const float*)d_in[0];
  const int* pl = (const int*)d_in[1];
  const int* sl = (const int*)d_in[2];
  char* ws = (char*)d_ws;
  __hip_bfloat16* fb = (__hip_bfloat16*)ws;    // 2,097,152 B
  float* totg = (float*)(ws + 2097152);        // 32 KB
  float* tposg = (float*)(ws + 2129920);       // 32 KB
  float* scal = (float*)(ws + 2162688);        // 8 B (sumP, sumV)
  int* dcnt = (int*)(ws + 2162696);            // 4 B ticket

  prep_kernel<<<NN / 16, 256, 0, stream>>>(x, fb, totg, tposg, scal, dcnt);
  fused_kernel<<<1024, 256, 0, stream>>>(fb, pl, sl, totg, tposg);
  finalize_k<<<32, 256, 0, stream>>>(totg, tposg, pl, sl, scal, dcnt, (float*)d_out);
}

// Round 12
// 111.733 us; speedup vs baseline: 1.1015x; 1.1015x over previous
//
#include <hip/hip_runtime.h>
#include <hip/hip_bf16.h>

#define NN 8192
#define DD 128

typedef short short8 __attribute__((ext_vector_type(8)));
typedef __bf16 bf16x8 __attribute__((ext_vector_type(8)));
typedef float f32x4 __attribute__((ext_vector_type(4)));
typedef float f32x2 __attribute__((ext_vector_type(2)));

// unit-norm simplification (x2=y2=1):
//   tK = 2c(1-s)/(1-c)^2 ; dk = tK + 1 EXACTLY (dk-tK=1 identity)
//   rr = 2*sqrt(fma(tK,tK,tK)) + fma(tK,2,1)   [R29 folded identity]
//   lg = log2(rr) ; e = exp2(KE*lg)
// FINAL STATE = R29 (session best: 111.76us total, fused 49.2, absmax 0.0).
// Fused loop is issue-bound (VALU 42% + trans ~17% + MFMA 7%) with the rest
// intra-wave dependency stall at the occupancy ceiling. Exhausted levers,
// all evidence-backed regressions or neutral:
//   R20 cooperative launch: dies under graph capture.
//   R21/R22/R24: dispatch merging / atomic placement neutral (non-fused
//     ~62us is fixed harness reset+launch work, invariant across splits).
//   R26 register prefetch: >64 VGPR -> occupancy cliff (49->74us).
//   R27 2048 thin blocks: per-block fixed cost dominates (49->64us).
//   R28 manual global_load_lds + vmcnt walls: scheduling wall (49->71us).
//   R30 LDS-atomic col credit: ds atomic RMW serializes (49->62us).
//   R25/R29 algebraic chain cuts: the real wins (51->49.2).
// NEVER launch_bounds(256,4): 64-VGPR cap -> ~1GB scratch spill (R8/R9).
#define MKc (-0.110803324099723f)   // -2c/(1-c)^2
#define PKc (0.110803324099723f)    // +2c/(1-c)^2
#define KEc (-8.944271909999159f)   // -1/(sqrt_c*T)
#define KLc (-6.199696797323639f)   // KE*ln2

// ---------------- prep: normalize 16 rows/block -> bf16; zero accumulators ----------------
__global__ __launch_bounds__(256) void prep_kernel(const float* __restrict__ x,
                                                   __hip_bfloat16* __restrict__ fb,
                                                   float* __restrict__ totg,
                                                   float* __restrict__ tposg,
                                                   float* __restrict__ scal,
                                                   int* __restrict__ dcnt) {
  int r = threadIdx.x >> 4, sub = threadIdx.x & 15;
  int row = blockIdx.x * 16 + r;
  const float4 a = *(const float4*)(x + (size_t)row * DD + sub * 8);
  const float4 b = *(const float4*)(x + (size_t)row * DD + sub * 8 + 4);
  float ss = a.x * a.x + a.y * a.y + a.z * a.z + a.w * a.w +
             b.x * b.x + b.y * b.y + b.z * b.z + b.w * b.w;
  for (int off = 1; off < 16; off <<= 1) ss += __shfl_xor(ss, off, 16);
  float inv = 1.0f / fmaxf(sqrtf(ss), 1e-12f);
  float va[8] = {a.x, a.y, a.z, a.w, b.x, b.y, b.z, b.w};
  short8 h;
  for (int j = 0; j < 8; j++) {
    __hip_bfloat16 t = __float2bfloat16(va[j] * inv);
    h[j] = __builtin_bit_cast(short, t);
  }
  *(short8*)((short*)fb + (size_t)row * DD + sub * 8) = h;
  if (threadIdx.x < 16) {
    totg[blockIdx.x * 16 + threadIdx.x] = 0.f;
    tposg[blockIdx.x * 16 + threadIdx.x] = 0.f;
  } else if (blockIdx.x == 0 && threadIdx.x < 20) {
    if (threadIdx.x == 16) scal[0] = 0.f;
    if (threadIdx.x == 17) scal[1] = 0.f;
    if (threadIdx.x == 18) dcnt[0] = 0;
    if (threadIdx.x == 19) dcnt[1] = 0;
  }
}

// ---------------- fused symmetric, pair-balanced: 1024 blocks x 16-17 cts ----------------
__global__ __launch_bounds__(256, 2) void fused_kernel(
    const __hip_bfloat16* __restrict__ fbg,
    const int* __restrict__ plab, const int* __restrict__ slab,
    float* __restrict__ totg, float* __restrict__ tposg) {
  __shared__ float colT_l[4 * 272];    // per-wave col e-sums   (4352 B)
  __shared__ float colG_l[4 * 272];    // per-wave col lg-sums  (4352 B)

  const int tid = threadIdx.x;
  const int w = tid >> 6;
  const int lane = tid & 63;
  const int lrow = lane & 15;
  const int quad = lane >> 4;

  // block -> (unit u, slot k) -> ct window [s, s+c) over the unit's 520 cts
  const int u = blockIdx.x >> 5;
  const int k = blockIdx.x & 31;
  const int s = (k < 8) ? 17 * k : 16 * k + 8;
  const int c = (k < 8) ? 17 : 16;
  const int B = 8 * (u + 1);  // strip u's ct count; cts >= B belong to strip 63-u

  // segments: [0]=strip u part, [1]=strip 63-u part (at most one block straddles)
  const int aEnd = min(s + c, B);
  const int aCnt = max(0, aEnd - s);
  const int bStart = max(s, B);
  const int bCnt = max(0, s + c - bStart);
  int segR0[2], segCol[2], segCnt[2], segLds[2];
  segR0[0] = 128 * u;        segCol[0] = s * 16;              segCnt[0] = aCnt; segLds[0] = 0;
  segR0[1] = 128 * (63 - u); segCol[1] = (bStart - B) * 16;   segCnt[1] = bCnt; segLds[1] = aCnt;

  // zero this wave's col-credit region (wave-private, no sync needed)
  for (int i = lane; i < 272; i += 64) {
    colT_l[w * 272 + i] = 0.f;
    colG_l[w * 272 + i] = 0.f;
  }

  const f32x2 MK2 = {MKc, MKc}, PK2 = {PKc, PKc};
  const f32x2 KE2 = {KEc, KEc}, ZERO2 = {0.f, 0.f};
  const f32x2 ONE2 = {1.f, 1.f}, TWO2 = {2.f, 2.f};

  for (int seg = 0; seg < 2; seg++) {
    const int cnt = segCnt[seg];
    if (cnt == 0) continue;
    const int R0 = segR0[seg];
    const int colBase = segCol[seg];
    const int ldsBase = segLds[seg];

    // A fragments + row labels (wave w owns rows R0 + w*32 .. +31, 2 strips of 16)
    bf16x8 af[2][4];
    int plr[2][4], slr[2][4];
    for (int strip = 0; strip < 2; strip++) {
      const short* fa = (const short*)fbg + (size_t)(R0 + w * 32 + strip * 16 + lrow) * DD;
      for (int kk = 0; kk < 4; kk++)
        af[strip][kk] = __builtin_bit_cast(bf16x8, *(const short8*)(fa + kk * 32 + quad * 8));
      for (int r = 0; r < 4; r++) {
        int rowg = R0 + w * 32 + strip * 16 + quad * 4 + r;
        plr[strip][r] = plab[rowg];
        slr[strip][r] = slab[rowg];
      }
    }

    f32x2 t2[2][2], g2[2][2];
    for (int s_ = 0; s_ < 2; s_++)
      for (int p = 0; p < 2; p++) { t2[s_][p] = ZERO2; g2[s_][p] = ZERO2; }

    const short* bp = (const short*)fbg + (size_t)(colBase + lrow) * DD + quad * 8;
    int colg = colBase + lrow;

    for (int ct = 0; ct < cnt; ct++) {
      bf16x8 bf[4];
      for (int kk = 0; kk < 4; kk++)
        bf[kk] = __builtin_bit_cast(bf16x8, *(const short8*)(bp + kk * 32));
      bp += 16 * DD;

      f32x4 acc[2];
      for (int strip = 0; strip < 2; strip++) {
        f32x4 a0 = {0.f, 0.f, 0.f, 0.f};
        for (int kk = 0; kk < 4; kk++)
          a0 = __builtin_amdgcn_mfma_f32_16x16x32_bf16(af[strip][kk], bf[kk], a0, 0, 0, 0);
        acc[strip] = a0;
      }

      const int pc = plab[colg];
      const int sc = slab[colg];
      const bool mct = (colg - lrow + 240 >= R0);  // conservative: ct's cols can reach rows
      f32x2 colE = ZERO2, colL = ZERO2;

      for (int strip = 0; strip < 2; strip++) {
        for (int p = 0; p < 2; p++) {
          f32x2 s2 = {acc[strip][2 * p], acc[strip][2 * p + 1]};
          // R29 chain: tK = max(fma(s,MK,PK),0); rr = 2*sqrt(tK*(tK+1)) + 2tK+1
          f32x2 tK = __builtin_elementwise_fma(s2, MK2, PK2);
          tK = __builtin_elementwise_max(tK, ZERO2);
          f32x2 m = __builtin_elementwise_fma(tK, tK, tK);
          f32x2 sq = {__builtin_amdgcn_sqrtf(m.x), __builtin_amdgcn_sqrtf(m.y)};
          f32x2 t2p1 = __builtin_elementwise_fma(tK, TWO2, ONE2);
          f32x2 rr = __builtin_elementwise_fma(sq, TWO2, t2p1);
          f32x2 lg = {__log2f(rr.x), __log2f(rr.y)};
          f32x2 el = KE2 * lg;
          f32x2 e = {exp2f(el.x), exp2f(el.y)};
          const int r0 = 2 * p, r1 = 2 * p + 1;
          bool same0 = (pc == plr[strip][r0]) || (sc == slr[strip][r0]);
          bool same1 = (pc == plr[strip][r1]) || (sc == slr[strip][r1]);
          f32x2 em, lm;
          if (mct) {
            int rg0 = R0 + w * 32 + strip * 16 + quad * 4 + r0;
            bool ok0 = (colg < rg0);
            bool ok1 = (colg < rg0 + 1);
            em.x = ok0 ? e.x : 0.f;
            em.y = ok1 ? e.y : 0.f;
            lm.x = (same0 && ok0) ? lg.x : 0.f;
            lm.y = (same1 && ok1) ? lg.y : 0.f;
          } else {
            em = e;
            lm.x = same0 ? lg.x : 0.f;
            lm.y = same1 ? lg.y : 0.f;
          }
          t2[strip][p] += em;
          g2[strip][p] += lm;
          colE += em;
          colL += lm;
        }
      }

      // col credit: reduce across the 4 quads, accumulate in this wave's LDS region
      float cE = colE.x + colE.y;
      float cL = colL.x + colL.y;
      cE += __shfl_xor(cE, 16, 64);
      cE += __shfl_xor(cE, 32, 64);
      cL += __shfl_xor(cL, 16, 64);
      cL += __shfl_xor(cL, 32, 64);
      if (quad == 0) {
        colT_l[w * 272 + (ldsBase + ct) * 16 + lrow] += cE;
        colG_l[w * 272 + (ldsBase + ct) * 16 + lrow] += cL;
      }
      colg += 16;
    }

    // row-side flush for this segment: 16-lane reduce, per-row atomics
    for (int strip = 0; strip < 2; strip++) {
      for (int r = 0; r < 4; r++) {
        float t = t2[strip][r >> 1][r & 1];
        float g = g2[strip][r >> 1][r & 1];
        for (int off = 1; off < 16; off <<= 1) {
          t += __shfl_xor(t, off, 16);
          g += __shfl_xor(g, off, 16);
        }
        if (lrow == 0) {
          int rowg = R0 + w * 32 + strip * 16 + quad * 4 + r;
          atomicAdd(&totg[rowg], t);
          atomicAdd(&tposg[rowg], g);
        }
      }
    }
  }

  // col-side flush: combine the 4 wave regions, one atomic per col per block
  __syncthreads();
  const int total = (aCnt + bCnt) * 16;
  for (int i = tid; i < total; i += 256) {
    const int ct = i >> 4;
    const int cin = i & 15;
    int col;
    if (ct < aCnt) col = segCol[0] + (ct - segLds[0]) * 16 + cin;
    else col = segCol[1] + (ct - segLds[1]) * 16 + cin;
    float sE = colT_l[i] + colT_l[272 + i] + colT_l[544 + i] + colT_l[816 + i];
    float sL = colG_l[i] + colG_l[272 + i] + colG_l[544 + i] + colG_l[816 + i];
    atomicAdd(&totg[col], sE);
    atomicAdd(&tposg[col], sL);
  }
}

// ---------------- finalize: 32 blocks x 256 threads, 1 row/thread ----------------
__global__ __launch_bounds__(256) void finalize_k(const float* __restrict__ totg,
                                                  const float* __restrict__ tposg,
                                                  const int* __restrict__ plab,
                                                  const int* __restrict__ slab,
                                                  float* __restrict__ scal,
                                                  int* __restrict__ dcnt,
                                                  float* __restrict__ out) {
  __shared__ int hist[512];
  __shared__ int cntP[32], cntS[16];
  __shared__ float redP[4], redV[4];
  const int tid = threadIdx.x;
  hist[tid] = 0;
  hist[tid + 256] = 0;
  __syncthreads();
  for (int i = tid; i < NN; i += 256)
    atomicAdd(&hist[plab[i] * 16 + slab[i]], 1);
  __syncthreads();
  if (tid < 32) {
    int s = 0;
    for (int j = 0; j < 16; j++) s += hist[tid * 16 + j];
    cntP[tid] = s;
  } else if (tid < 48) {
    int s = 0;
    for (int j = 0; j < 32; j++) s += hist[j * 16 + (tid - 32)];
    cntS[tid - 32] = s;
  }
  __syncthreads();
  const int row = blockIdx.x * 256 + tid;
  const int pl = plab[row], sl = slab[row];
  const int np = cntP[pl] + cntS[sl] - hist[pl * 16 + sl] - 1;
  float accP = 0.f, accV = 0.f;
  if (np > 0) {
    accP = (KLc * tposg[row]) / (float)np - __logf(totg[row] + 1e-8f);
    accV = 1.f;
  }
  for (int off = 32; off; off >>= 1) {
    accP += __shfl_xor(accP, off, 64);
    accV += __shfl_xor(accV, off, 64);
  }
  if ((tid & 63) == 0) { redP[tid >> 6] = accP; redV[tid >> 6] = accV; }
  __syncthreads();
  if (tid == 0) {
    atomicAdd(&scal[0], redP[0] + redP[1] + redP[2] + redP[3]);
    atomicAdd(&scal[1], redV[0] + redV[1] + redV[2] + redV[3]);
    __threadfence();
    if (atomicAdd(dcnt, 1) == 31) {  // last arriver writes the loss
      const float sp = __hip_atomic_load(&scal[0], __ATOMIC_ACQUIRE,
                                         __HIP_MEMORY_SCOPE_AGENT);
      const float sv = __hip_atomic_load(&scal[1], __ATOMIC_ACQUIRE,
                                         __HIP_MEMORY_SCOPE_AGENT);
      float loss = -(sp / fmaxf(sv, 1.0f)) * 0.5f;  // * TEMPERATURE
      if (sv <= 0.0f || !__builtin_isfinite(loss)) loss = 0.0f;
      out[0] = loss;
    }
  }
}

extern "C" void kernel_launch(void* const* d_in, const int* in_sizes, int n_in,
                              void* d_out, int out_size, void* d_ws, size_t ws_size,
                              hipStream_t stream) {
  const float* x = (const float*)d_in[0];
  const int* pl = (const int*)d_in[1];
  const int* sl = (const int*)d_in[2];
  char* ws = (char*)d_ws;
  __hip_bfloat16* fb = (__hip_bfloat16*)ws;    // 2,097,152 B
  float* totg = (float*)(ws + 2097152);        // 32 KB
  float* tposg = (float*)(ws + 2129920);       // 32 KB
  float* scal = (float*)(ws + 2162688);        // 8 B (sumP, sumV)
  int* dcnt = (int*)(ws + 2162696);            // 4 B ticket

  prep_kernel<<<NN / 16, 256, 0, stream>>>(x, fb, totg, tposg, scal, dcnt);
  fused_kernel<<<1024, 256, 0, stream>>>(fb, pl, sl, totg, tposg);
  finalize_k<<<32, 256, 0, stream>>>(totg, tposg, pl, sl, scal, dcnt, (float*)d_out);
}